// Round 1
// baseline (5386.519 us; speedup 1.0000x reference)
//
#include <hip/hip_runtime.h>

#define BS    32
#define MDIM  256
#define NDIM  512
#define ITERS 1000
#define WPB   4      // wgs per batch (prologue partitioning only)
#define BLK   512
#define ALPHA 0.02f
#define BETA  0.02f

// ---- LDS layout (floats) — PROLOGUE ONLY ----
// A-tile [32 m-rows][ATS] (ATS=520: 16B-aligned rows, pad vs power-of-2) + b tile.
#define ATS      520
#define BT_OFF   (32 * ATS)
#define SMEM_FL  (BT_OFF + 32)          // 66,688 B

// Exchange slab: [2 parity][BS][512] floats. Mantissa-tagged words (low 8 bits
// = (k+1)&255): every 4B word self-validates (proven R6/R7). Agent-scope
// relaxed atomics only — protocol identical to the 1541us kernel; only the
// participant granularity changed (32 waves/batch instead of 4 wgs/batch).
// Drift bound < 2 iterations holds unchanged: a wave passes poll k only after
// ALL waves stored tag k+1, so parity k&1 is never overwritten while needed.
#define SLAB_FL  (2 * BS * NDIM)

__device__ __forceinline__ unsigned ld_coh_u32(const void* p) {
  return __hip_atomic_load(reinterpret_cast<const unsigned*>(p),
                           __ATOMIC_RELAXED, __HIP_MEMORY_SCOPE_AGENT);
}
__device__ __forceinline__ void st_coh_u32(void* p, unsigned v) {
  __hip_atomic_store(reinterpret_cast<unsigned*>(p), v,
                     __ATOMIC_RELAXED, __HIP_MEMORY_SCOPE_AGENT);
}
__device__ __forceinline__ unsigned tagf(float v, unsigned tag) {
  return (__float_as_uint(v) & ~0xFFu) | tag;
}

// Wave-autonomous PDHG: each wave owns 16 rows of G = A^T A (lane holds
// acc[16 rows][8 cols], cols [8*lane, 8*lane+8)). Iteration loop has NO
// __syncthreads and NO LDS: poll 8 words -> 128 FMA -> shuffle butterfly
// reduce -> lane<16 update t,x and store 1 tagged word.
__global__ __launch_bounds__(BLK, 2) void pdhg_kernel(
    const float* __restrict__ A, const float* __restrict__ Bvec,
    float* __restrict__ out, float* __restrict__ slab)
{
  __shared__ float smem[SMEM_FL];
  const int tid   = threadIdx.x;
  const int bid   = blockIdx.x;
  const int batch = bid & (BS - 1);
  const int slice = bid >> 5;            // 0..3
  const int lane  = tid & 63;
  const int widx  = tid >> 6;            // wave in wg, 0..7
  const int rowbase = slice * 128 + widx * 16;   // wave's 16 G-rows
  const int row_own = lane & 15;                 // lane's row (4-redundant)
  const int i_own   = rowbase + row_own;
  const int c0      = lane * 8;                  // lane's 8 G-cols

  // ================= PROLOGUE: G rows in regs, c = A^T b per-lane ==========
  float acc[16][8];
#pragma unroll
  for (int r = 0; r < 16; ++r)
#pragma unroll
    for (int c = 0; c < 8; ++c) acc[r][c] = 0.f;
  float cacc = 0.f;                      // c[i_own], identical across the 4 redundant lanes

  const float* Ag = A + (size_t)batch * MDIM * NDIM;

  for (int mt = 0; mt < MDIM / 32; ++mt) {
    // stage A[mt*32..+32, :] plainly as [32][ATS] (coalesced float4)
#pragma unroll 4
    for (int q = 0; q < 8; ++q) {
      int f  = q * 512 + tid;            // float4 index in 32x512 tile
      int mm = f >> 7;
      int j  = (f & 127) << 2;
      float4 v = *reinterpret_cast<const float4*>(
          Ag + (size_t)(mt * 32 + mm) * NDIM + j);
      *reinterpret_cast<float4*>(&smem[mm * ATS + j]) = v;
    }
    if (tid < 32) smem[BT_OFF + tid] = Bvec[batch * MDIM + mt * 32 + tid];
    __syncthreads();

#pragma unroll 2
    for (int m = 0; m < 32; ++m) {
      const float* row = &smem[m * ATS];
      // ai[16]: wave-broadcast reads (conflict-free)
      float4 a0 = *reinterpret_cast<const float4*>(row + rowbase);
      float4 a1 = *reinterpret_cast<const float4*>(row + rowbase + 4);
      float4 a2 = *reinterpret_cast<const float4*>(row + rowbase + 8);
      float4 a3 = *reinterpret_cast<const float4*>(row + rowbase + 12);
      float ai[16] = {a0.x,a0.y,a0.z,a0.w, a1.x,a1.y,a1.z,a1.w,
                      a2.x,a2.y,a2.z,a2.w, a3.x,a3.y,a3.z,a3.w};
      // aj[8]: per-lane cols (32B stride — LDS-BW bound, prologue only)
      float4 j0 = *reinterpret_cast<const float4*>(row + c0);
      float4 j1 = *reinterpret_cast<const float4*>(row + c0 + 4);
      float aj[8] = {j0.x,j0.y,j0.z,j0.w, j1.x,j1.y,j1.z,j1.w};
      float bm  = smem[BT_OFF + m];
      float aio = row[i_own];            // own-row value for c accumulation
#pragma unroll
      for (int r = 0; r < 16; ++r)
#pragma unroll
        for (int c = 0; c < 8; ++c) acc[r][c] = fmaf(ai[r], aj[c], acc[r][c]);
      cacc = fmaf(aio, bm, cacc);
    }
    __syncthreads();
  }

  // ================= ITERATION (barrier-free, LDS-free) ====================
  float x = 0.f, t = 0.f;
  float*       myslot = slab + batch * NDIM + i_own;  // store (lane<16), + parity
  const float* myrd   = slab + batch * NDIM + c0;     // poll base: 8 words

  for (int k = 0; k < ITERS; ++k) {
    float y  = x - ALPHA * t;
    float xn = fmaxf(y - ALPHA, 0.f) - fmaxf(-y - ALPHA, 0.f);
    if (k == ITERS - 1) { x = xn; break; }

    const int      par = (k & 1) * BS * NDIM;
    const unsigned tag = (unsigned)(k + 1) & 0xFFu;
    float wv = 2.f * xn - x;
    x = xn;
    if (lane < 16) st_coh_u32(myslot + par, tagf(wv, tag));

    // poll this lane's 8 w-words; every word self-validates via mantissa tag
    unsigned q[8];
    unsigned bad;
    do {
      bad = 0u;
#pragma unroll
      for (int j = 0; j < 8; ++j) {
        q[j] = ld_coh_u32(myrd + par + j);
        bad |= (q[j] ^ tag);
      }
    } while (bad & 0xFFu);

    float wr[8];
#pragma unroll
    for (int j = 0; j < 8; ++j) wr[j] = __uint_as_float(q[j]);

    // S[r] = G[rowbase+r, c0..c0+8) . w[c0..c0+8)
    float S[16];
#pragma unroll
    for (int r = 0; r < 16; ++r) {
      float p = acc[r][0] * wr[0];
#pragma unroll
      for (int c = 1; c < 8; ++c) p = fmaf(acc[r][c], wr[c], p);
      S[r] = p;
    }

    // value-halving butterfly: after stages 1,2,4,8 lane holds row (lane&15)
    // summed over its 16-lane group; xor16+xor32 complete the sum. Final two
    // stages are single commutative adds -> all 4 redundant lanes get
    // bit-identical results (t stays exactly consistent).
    const bool b0 = (lane & 1), b1 = (lane & 2), b2 = (lane & 4), b3 = (lane & 8);
    float T[8];
#pragma unroll
    for (int i = 0; i < 8; ++i) {
      float keep = b0 ? S[2*i+1] : S[2*i];
      float send = b0 ? S[2*i]   : S[2*i+1];
      T[i] = keep + __shfl_xor(send, 1);
    }
    float U[4];
#pragma unroll
    for (int i = 0; i < 4; ++i) {
      float keep = b1 ? T[2*i+1] : T[2*i];
      float send = b1 ? T[2*i]   : T[2*i+1];
      U[i] = keep + __shfl_xor(send, 2);
    }
    float V[2];
#pragma unroll
    for (int i = 0; i < 2; ++i) {
      float keep = b2 ? U[2*i+1] : U[2*i];
      float send = b2 ? U[2*i]   : U[2*i+1];
      V[i] = keep + __shfl_xor(send, 4);
    }
    float Wv;
    {
      float keep = b3 ? V[1] : V[0];
      float send = b3 ? V[0] : V[1];
      Wv = keep + __shfl_xor(send, 8);
    }
    Wv += __shfl_xor(Wv, 16);
    Wv += __shfl_xor(Wv, 32);

    t += BETA * (Wv - cacc);             // t_{k+1} = t_k + beta*(G w - c)
  }

  // ---- epilogue: canonical lanes write x slice ----
  if (lane < 16) out[(size_t)batch * NDIM + i_own] = x;
}

extern "C" void kernel_launch(void* const* d_in, const int* in_sizes, int n_in,
                              void* d_out, int out_size, void* d_ws, size_t ws_size,
                              hipStream_t stream) {
  const float* A = (const float*)d_in[0];
  const float* b = (const float*)d_in[1];
  float* out  = (float*)d_out;
  float* slab = (float*)d_ws;                    // 128 KiB w-exchange slab

  hipMemsetAsync(d_ws, 0, SLAB_FL * sizeof(float), stream);  // tag 0 != 1,2

  void* args[] = {(void*)&A, (void*)&b, (void*)&out, (void*)&slab};
  hipLaunchCooperativeKernel((const void*)pdhg_kernel, dim3(BS * WPB), dim3(BLK),
                             args, 0, stream);
}

// Round 3
// 1676.235 us; speedup vs baseline: 3.2135x; 3.2135x over previous
//
#include <hip/hip_runtime.h>

#define BS    32
#define MDIM  256
#define NDIM  512
#define ITERS 1000
#define WPB   4      // wgs per batch; each owns 128 rows of G
#define BLK   512
#define ALPHA 0.02f
#define BETA  0.02f

// ---- LDS layout (floats) ----
// Prologue: A-tile [32 m-rows][ATS=520] + b tile. Iteration: w stage reuses
// the first 512 floats (prologue finished by then).
#define ATS      520
#define BT_OFF   (32 * ATS)
#define SMEM_FL  (BT_OFF + 32)          // 66,688 B

// Exchange slab: [2 parity][BS][512] floats. Mantissa-tagged words (low 8 bits
// = (k+1)&255): every 4B word self-validates (proven R6/R7). Agent-scope
// relaxed atomics only. COALESCED polling: thread polls word tid -> a wave's
// poll is 64 consecutive dwords = 4 lines (R1's 8-word/lane strided poll was
// 32 lines/instr and saturated LLC queues -> 2.5x regression).
// [R3 NOTE: identical resubmission of the R2 kernel — R2's bench died on
// container acquire ("failed twice"), no counters; kernel re-audited for
// hang paths (barrier divergence, spin liveness, parity overwrite): none.]
#define SLAB_FL  (2 * BS * NDIM)

__device__ __forceinline__ unsigned ld_coh_u32(const void* p) {
  return __hip_atomic_load(reinterpret_cast<const unsigned*>(p),
                           __ATOMIC_RELAXED, __HIP_MEMORY_SCOPE_AGENT);
}
__device__ __forceinline__ void st_coh_u32(void* p, unsigned v) {
  __hip_atomic_store(reinterpret_cast<unsigned*>(p), v,
                     __ATOMIC_RELAXED, __HIP_MEMORY_SCOPE_AGENT);
}
__device__ __forceinline__ unsigned tagf(float v, unsigned tag) {
  return (__float_as_uint(v) & ~0xFFu) | tag;
}

// Hybrid structure: wg-level coalesced poll + LDS w-stage (1 word/thread),
// per-WAVE register-resident G (16 rows x 512 cols; lane holds
// acc[16][8] for cols {64c+lane}), in-register butterfly reduce.
// ONE __syncthreads per iteration; no LDS partials.
__global__ __launch_bounds__(BLK, 1) void pdhg_kernel(
    const float* __restrict__ A, const float* __restrict__ Bvec,
    float* __restrict__ out, float* __restrict__ slab)
{
  __shared__ float smem[SMEM_FL];
  const int tid   = threadIdx.x;
  const int bid   = blockIdx.x;
  const int batch = bid & (BS - 1);
  const int slice = bid >> 5;            // 0..3
  const int lane  = tid & 63;
  const int widx  = tid >> 6;            // wave in wg, 0..7
  const int rowbase = slice * 128 + widx * 16;   // wave's 16 G-rows
  const int row_own = lane & 15;                 // lane's row (4-redundant)
  const int i_own   = rowbase + row_own;

  // ================= PROLOGUE: G rows in regs, c = A^T b per-lane ==========
  float acc[16][8];                      // acc[r][c] = G[rowbase+r][64c+lane]
#pragma unroll
  for (int r = 0; r < 16; ++r)
#pragma unroll
    for (int c = 0; c < 8; ++c) acc[r][c] = 0.f;
  float cacc = 0.f;                      // c[i_own], identical across redundant lanes

  const float* Ag = A + (size_t)batch * MDIM * NDIM;

  for (int mt = 0; mt < MDIM / 32; ++mt) {
    // stage A[mt*32..+32, :] plainly as [32][ATS] (coalesced float4)
#pragma unroll 4
    for (int q = 0; q < 8; ++q) {
      int f  = q * 512 + tid;            // float4 index in 32x512 tile
      int mm = f >> 7;
      int j  = (f & 127) << 2;
      float4 v = *reinterpret_cast<const float4*>(
          Ag + (size_t)(mt * 32 + mm) * NDIM + j);
      *reinterpret_cast<float4*>(&smem[mm * ATS + j]) = v;
    }
    if (tid < 32) smem[BT_OFF + tid] = Bvec[batch * MDIM + mt * 32 + tid];
    __syncthreads();

#pragma unroll 2
    for (int m = 0; m < 32; ++m) {
      const float* row = &smem[m * ATS];
      // ai[16]: wave-broadcast float4 reads (free)
      float4 a0 = *reinterpret_cast<const float4*>(row + rowbase);
      float4 a1 = *reinterpret_cast<const float4*>(row + rowbase + 4);
      float4 a2 = *reinterpret_cast<const float4*>(row + rowbase + 8);
      float4 a3 = *reinterpret_cast<const float4*>(row + rowbase + 12);
      float ai[16] = {a0.x,a0.y,a0.z,a0.w, a1.x,a1.y,a1.z,a1.w,
                      a2.x,a2.y,a2.z,a2.w, a3.x,a3.y,a3.z,a3.w};
      // aj[8]: strided cols 64c+lane — consecutive per lane, conflict-free
      float aj[8];
#pragma unroll
      for (int c = 0; c < 8; ++c) aj[c] = row[64 * c + lane];
      float bm  = smem[BT_OFF + m];
      float aio = row[i_own];            // own-row value (same-addr broadcast)
#pragma unroll
      for (int r = 0; r < 16; ++r)
#pragma unroll
        for (int c = 0; c < 8; ++c) acc[r][c] = fmaf(ai[r], aj[c], acc[r][c]);
      cacc = fmaf(aio, bm, cacc);
    }
    __syncthreads();
  }

  // ================= ITERATION ============================================
  float x = 0.f, t = 0.f;
  float*       myslot = slab + batch * NDIM + i_own;  // store (lane<16), +parity
  const float* myrd   = slab + batch * NDIM + tid;    // coalesced poll: word tid

  for (int k = 0; k < ITERS; ++k) {
    float y  = x - ALPHA * t;
    float xn = fmaxf(y - ALPHA, 0.f) - fmaxf(-y - ALPHA, 0.f);
    if (k == ITERS - 1) { x = xn; break; }

    const int      par = (k & 1) * BS * NDIM;
    const unsigned tag = (unsigned)(k + 1) & 0xFFu;
    float wv = 2.f * xn - x;
    x = xn;
    if (lane < 16) st_coh_u32(myslot + par, tagf(wv, tag));

    // poll this thread's single word (self-validating mantissa tag)
    unsigned q;
    do { q = ld_coh_u32(myrd + par); } while ((q ^ tag) & 0xFFu);

    // stage into LDS. Writing w[k+1] here cannot race a slow wave's w[k]
    // reads: our poll passed only because ALL waves stored tag k+1, which
    // each wave does only AFTER finishing its iter-(k-1) LDS reads. So one
    // barrier (write->read) suffices; no trailing barrier needed.
    smem[tid] = __uint_as_float(q);
    __syncthreads();

    float wr[8];
#pragma unroll
    for (int c = 0; c < 8; ++c) wr[c] = smem[64 * c + lane];  // 2/bank = free

    // S[r] = sum_c G[rowbase+r][64c+lane] * w[64c+lane]  (partial over lane)
    float S[16];
#pragma unroll
    for (int r = 0; r < 16; ++r) {
      float p = acc[r][0] * wr[0];
#pragma unroll
      for (int c = 1; c < 8; ++c) p = fmaf(acc[r][c], wr[c], p);
      S[r] = p;
    }

    // value-halving butterfly: after stages 1,2,4,8 lane holds row (lane&15)
    // summed over its 16-lane group; xor16+xor32 complete the sum. Final two
    // stages are single commutative adds -> all 4 redundant lanes get
    // bit-identical results (t stays exactly consistent).
    const bool b0 = (lane & 1), b1 = (lane & 2), b2 = (lane & 4), b3 = (lane & 8);
    float T[8];
#pragma unroll
    for (int i = 0; i < 8; ++i) {
      float keep = b0 ? S[2*i+1] : S[2*i];
      float send = b0 ? S[2*i]   : S[2*i+1];
      T[i] = keep + __shfl_xor(send, 1);
    }
    float U[4];
#pragma unroll
    for (int i = 0; i < 4; ++i) {
      float keep = b1 ? T[2*i+1] : T[2*i];
      float send = b1 ? T[2*i]   : T[2*i+1];
      U[i] = keep + __shfl_xor(send, 2);
    }
    float V[2];
#pragma unroll
    for (int i = 0; i < 2; ++i) {
      float keep = b2 ? U[2*i+1] : U[2*i];
      float send = b2 ? U[2*i]   : U[2*i+1];
      V[i] = keep + __shfl_xor(send, 4);
    }
    float Wv;
    {
      float keep = b3 ? V[1] : V[0];
      float send = b3 ? V[0] : V[1];
      Wv = keep + __shfl_xor(send, 8);
    }
    Wv += __shfl_xor(Wv, 16);
    Wv += __shfl_xor(Wv, 32);

    t += BETA * (Wv - cacc);             // t_{k+1} = t_k + beta*(G w - c)
  }

  // ---- epilogue: canonical lanes write x slice ----
  if (lane < 16) out[(size_t)batch * NDIM + i_own] = x;
}

extern "C" void kernel_launch(void* const* d_in, const int* in_sizes, int n_in,
                              void* d_out, int out_size, void* d_ws, size_t ws_size,
                              hipStream_t stream) {
  const float* A = (const float*)d_in[0];
  const float* b = (const float*)d_in[1];
  float* out  = (float*)d_out;
  float* slab = (float*)d_ws;                    // 128 KiB w-exchange slab

  hipMemsetAsync(d_ws, 0, SLAB_FL * sizeof(float), stream);  // tag 0 != 1,2

  void* args[] = {(void*)&A, (void*)&b, (void*)&out, (void*)&slab};
  hipLaunchCooperativeKernel((const void*)pdhg_kernel, dim3(BS * WPB), dim3(BLK),
                             args, 0, stream);
}